// Round 3
// baseline (334.980 us; speedup 1.0000x reference)
//
#include <hip/hip_runtime.h>
#include <stdint.h>

#define B_ 64
#define C_ 4
#define R_ 64
#define E_ 512
#define P_ 4
#define OS_ 256
#define L_ (R_*E_)        // 32768
#define K_ (L_*E8_DUMMY)  // placeholder avoided below
#undef K_
#define K_ 131072         // L_*P_
#define M_ 256            // B_*C_

#define BM 256
#define BN 128
#define BK 32
#define Z_ 256            // split-K slices; grid = 512 = 2 blocks/CU
#define KCH (K_/Z_)       // 512
#define ITERS (KCH/BK)    // 16

typedef float  floatx4 __attribute__((ext_vector_type(4)));
typedef short  shortx8 __attribute__((ext_vector_type(8)));

// async global->LDS, 16 B per lane; LDS dest is wave-uniform base + lane*16
#define GLDS16(g, l) __builtin_amdgcn_global_load_lds(                      \
    (const __attribute__((address_space(1))) void*)(g),                     \
    (__attribute__((address_space(3))) void*)(l), 16, 0, 0)

static __device__ __forceinline__ unsigned short f2bf(float f) {
  union { float f; unsigned int u; } v; v.f = f;
  unsigned int u = v.u;
  u += 0x7fffu + ((u >> 16) & 1u);   // RNE
  return (unsigned short)(u >> 16);
}

// ---------------------------------------------------------------------------
// prep = build_A (blocks 0..2047)  ||  convW (blocks 2048..4095), merged so
// convW's pure-BW streaming overlaps build_A's VALU/LDS-bound gather work.
//
// A2 layout (k-slab granules): A2[k8][m][8] bf16, k8 = k/8. A gemm a-fragment
// for lane l is exactly granule (k8, m): 16 B contiguous. A BK=32 tile is
// 16 KB fully contiguous in HBM.
// W2: identical layout with n in place of m (produced by convW).
// ---------------------------------------------------------------------------
__global__ __launch_bounds__(512) void prep(
    const float* __restrict__ x, const int* __restrict__ rxd_perm,
    const int* __restrict__ e_idx, const float* __restrict__ signs,
    const float* __restrict__ W,
    unsigned short* __restrict__ A2, unsigned short* __restrict__ W2) {
  __shared__ __align__(16) unsigned char smem[64 * 33 * 16];   // 33 KB union
  const int t = threadIdx.x;

  if (blockIdx.x < 2048) {
    // ---------------- build_A: block = (bc-group of 8, single r) ------------
    const int blk = blockIdx.x;       // bcg*64 + r
    const int bcg = blk >> 6;         // 0..31
    const int r   = blk & 63;
    float (*xr)[E_] = (float(*)[E_])smem;   // 8 rows x 512 f32 = 16 KB
    const int pr = rxd_perm[r];

    #pragma unroll
    for (int i = 0; i < 2; ++i) {     // 1024 float4 granules, 2 per thread
      const int q   = i * 512 + t;
      const int row = q >> 7;         // 0..7 = bcLoc
      const int c4  = q & 127;
      const int bc  = bcg * 8 + row;
      *(float4*)(&xr[row][c4 * 4]) =
          *(const float4*)(x + ((size_t)bc * R_ + pr) * E_ + c4 * 4);
    }
    __syncthreads();

    const int bcLoc = t >> 6;         // 0..7
    const int lane  = t & 63;
    const int e0    = lane * 8;       // 8 consecutive e per thread
    const int bc    = bcg * 8 + bcLoc;
    const float* xp = xr[bcLoc];

    float v[4][8];
    #pragma unroll
    for (int i = 0; i < 8; ++i) {
      const uint4  ei = *(const uint4*)(e_idx + (size_t)(e0 + i) * 4);
      const float4 sg = *(const float4*)(signs + (size_t)(e0 + i) * 4);
      v[0][i] = xp[ei.x] * sg.x;
      v[1][i] = xp[ei.y] * sg.y;
      v[2][i] = xp[ei.z] * sg.z;
      v[3][i] = xp[ei.w] * sg.w;
    }

    // store granule (k8, bc); k8 = p*4096 + r*64 + lane
    const size_t gbase = (size_t)(r * 64 + lane) * 256 + bc;   // p=0 granule
    shortx8 o;

    // p=0: passthrough
    #pragma unroll
    for (int i = 0; i < 8; ++i) o[i] = (short)f2bf(v[0][i]);
    *(shortx8*)(A2 + gbase * 8) = o;

    // p=1: k=2 windows, first-max wins
    #pragma unroll
    for (int j = 0; j < 4; ++j) {
      const float a = v[1][2 * j], b = v[1][2 * j + 1];
      const bool first = (a >= b);
      o[2 * j]     = (short)f2bf(first ? a : 0.0f);
      o[2 * j + 1] = (short)f2bf(first ? 0.0f : b);
    }
    *(shortx8*)(A2 + (gbase + (size_t)4096 * 256) * 8) = o;

    // p=2: k=4 windows
    #pragma unroll
    for (int j = 0; j < 2; ++j) {
      int am = 0; float m = v[2][4 * j];
      #pragma unroll
      for (int i = 1; i < 4; ++i)
        if (v[2][4 * j + i] > m) { m = v[2][4 * j + i]; am = i; }
      #pragma unroll
      for (int i = 0; i < 4; ++i) o[4 * j + i] = (short)f2bf(i == am ? m : 0.0f);
    }
    *(shortx8*)(A2 + (gbase + (size_t)2 * 4096 * 256) * 8) = o;

    // p=3: k=8 window
    {
      int am = 0; float m = v[3][0];
      #pragma unroll
      for (int i = 1; i < 8; ++i)
        if (v[3][i] > m) { m = v[3][i]; am = i; }
      #pragma unroll
      for (int i = 0; i < 8; ++i) o[i] = (short)f2bf(i == am ? m : 0.0f);
    }
    *(shortx8*)(A2 + (gbase + (size_t)3 * 4096 * 256) * 8) = o;

  } else {
    // ---------------- convW: W[n][k] f32 -> W2[k8][n][8] bf16 ---------------
    const int cb = blockIdx.x - 2048; // 0..2047
    const int nb = cb & 7;            // 8 n-tiles of 32
    const int kb = cb >> 3;           // 256 k-tiles of 512
    const int nbase  = nb * 32;
    const int k8base = kb * 64;
    unsigned short* T = (unsigned short*)smem;  // granule (k8loc*33 + nloc)

    // phase 1: coalesced f32 reads (128 B/thread of one row), convert,
    // transpose into LDS (stride 33 granules kills write conflicts)
    const int nloc = t >> 4, seg = t & 15;
    const float* wp = W + (size_t)(nbase + nloc) * K_ + (size_t)kb * 512 + seg * 32;
    #pragma unroll
    for (int j = 0; j < 4; ++j) {
      const float4 a0 = *(const float4*)(wp + j * 8);
      const float4 a1 = *(const float4*)(wp + j * 8 + 4);
      shortx8 g;
      g[0] = (short)f2bf(a0.x); g[1] = (short)f2bf(a0.y);
      g[2] = (short)f2bf(a0.z); g[3] = (short)f2bf(a0.w);
      g[4] = (short)f2bf(a1.x); g[5] = (short)f2bf(a1.y);
      g[6] = (short)f2bf(a1.z); g[7] = (short)f2bf(a1.w);
      const int k8loc = seg * 4 + j;
      *(shortx8*)(&T[(k8loc * 33 + nloc) * 8]) = g;
    }
    __syncthreads();

    // phase 2: store granule-rows; per instruction lanes cover 128 B contiguous
    const int k8loc = t >> 3, part = t & 7;
    unsigned short* wdst = W2 + ((size_t)(k8base + k8loc) * 256 + nbase) * 8;
    #pragma unroll
    for (int j = 0; j < 4; ++j) {
      const int g = j * 8 + part;     // n-granule 0..31
      *(shortx8*)(wdst + (size_t)g * 8) = *(const shortx8*)(&T[(k8loc * 33 + g) * 8]);
    }
  }
}

// ---------------------------------------------------------------------------
// Split-K GEMM on k-slab layout: per iter GLDS 16 KB (A2) + 8 KB (W2), both
// fully contiguous in HBM (page-hit streaming); fragments read directly as
// 16-B granules (no swizzle, no conversion, no reg staging). Double-buffered,
// 48 KB LDS -> 2 blocks/CU.
// ---------------------------------------------------------------------------
__global__ __launch_bounds__(512, 4) void gemm_splitk(
    const unsigned short* __restrict__ A2, const unsigned short* __restrict__ W2,
    float* __restrict__ Pp) {
  __shared__ unsigned short As[2][4 * 256 * 8];   // 2 x 16 KB
  __shared__ unsigned short Ws[2][4 * 128 * 8];   // 2 x 8 KB
  const int t    = threadIdx.x;
  const int lane = t & 63;
  const int wv   = t >> 6;                  // 0..7

  // ids i and i+8 share z -> same XCD (round-robin heuristic)
  const int id = blockIdx.x;                // 0..511
  const int ny = (id >> 3) & 1;
  const int z  = (id & 7) | ((id >> 4) << 3);
  const int nBase = ny * BN;

  const int wm   = (wv >> 1) * 64;
  const int wn   = (wv & 1) * 64;
  const int lrow = lane & 15;
  const int quad = lane >> 4;

  floatx4 acc[4][4];
  #pragma unroll
  for (int i = 0; i < 4; ++i)
    #pragma unroll
    for (int j = 0; j < 4; ++j) acc[i][j] = {0.f, 0.f, 0.f, 0.f};

  auto stage = [&](int buf, int it) {
    const size_t g0 = (size_t)(z * 64 + it * 4) * 256;   // 4 slabs x 256 granules
    #pragma unroll
    for (int c = 0; c < 2; ++c) {
      const int slot = (wv * 2 + c) * 64 + lane;         // 0..1023
      GLDS16(A2 + (g0 + slot) * 8, &As[buf][slot * 8]);
    }
    const int wslot = wv * 64 + lane;                    // 0..511
    const int slab  = wslot >> 7;                        // uniform per wave-call
    const int nloc  = wslot & 127;
    GLDS16(W2 + (g0 + (size_t)slab * 256 + nBase + nloc) * 8, &Ws[buf][wslot * 8]);
  };
  auto compute = [&](int buf) {
    shortx8 af[4], wf[4];
    #pragma unroll
    for (int ti = 0; ti < 4; ++ti)
      af[ti] = *(const shortx8*)(&As[buf][(quad * 256 + wm + ti * 16 + lrow) * 8]);
    #pragma unroll
    for (int tj = 0; tj < 4; ++tj)
      wf[tj] = *(const shortx8*)(&Ws[buf][(quad * 128 + wn + tj * 16 + lrow) * 8]);
    #pragma unroll
    for (int ti = 0; ti < 4; ++ti)
      #pragma unroll
      for (int tj = 0; tj < 4; ++tj)
        acc[ti][tj] = __builtin_amdgcn_mfma_f32_16x16x32_bf16(
            af[ti], wf[tj], acc[ti][tj], 0, 0, 0);
  };

  stage(0, 0);
  __syncthreads();

  for (int it = 0; it < ITERS; ++it) {
    const int b = it & 1;
    if (it + 1 < ITERS) stage(b ^ 1, it + 1);  // fire-and-forget prefetch
    compute(b);
    __syncthreads();                            // vmcnt(0): buffer b^1 ready
  }

  // epilogue: plain stores of the split-K partial
  float* Pz = Pp + (size_t)z * (M_ * OS_);
  #pragma unroll
  for (int ti = 0; ti < 4; ++ti)
    #pragma unroll
    for (int tj = 0; tj < 4; ++tj)
      #pragma unroll
      for (int j = 0; j < 4; ++j) {
        const int m = wm + ti * 16 + quad * 4 + j;
        const int n = nBase + wn + tj * 16 + lrow;
        Pz[(size_t)m * OS_ + n] = acc[ti][tj][j];
      }
}

// out[m,n] = bias[n] + sum_z P[z,m,n]; 2-way z-split per output doubles
// bytes-in-flight; halves combined through LDS.
__global__ __launch_bounds__(256) void reduce_out(
    const float* __restrict__ Pp, const float* __restrict__ bias,
    float* __restrict__ out) {
  __shared__ float4 part[128];
  const int t    = threadIdx.x;               // 0..255
  const int i4   = blockIdx.x * 128 + (t & 127);   // 0..16383
  const int half = t >> 7;
  const float* p = Pp + (size_t)i4 * 4 + (size_t)half * 128 * (M_ * OS_);
  float4 s = {0.f, 0.f, 0.f, 0.f};
  #pragma unroll 8
  for (int zz = 0; zz < 128; ++zz) {
    const float4 v = *(const float4*)(p + (size_t)zz * (M_ * OS_));
    s.x += v.x; s.y += v.y; s.z += v.z; s.w += v.w;
  }
  if (half) part[t & 127] = s;
  __syncthreads();
  if (!half) {
    const float4 q = part[t];
    const float4 bb = *(const float4*)(bias + ((i4 * 4) & (OS_ - 1)));
    float4 o = {s.x + q.x + bb.x, s.y + q.y + bb.y,
                s.z + q.z + bb.z, s.w + q.w + bb.w};
    *(float4*)(out + (size_t)i4 * 4) = o;
  }
}

extern "C" void kernel_launch(void* const* d_in, const int* in_sizes, int n_in,
                              void* d_out, int out_size, void* d_ws, size_t ws_size,
                              hipStream_t stream) {
  const float* x        = (const float*)d_in[0];
  const int*   rxd_perm = (const int*)d_in[1];
  const int*   e_idx    = (const int*)d_in[2];
  const float* signs    = (const float*)d_in[3];
  const float* W        = (const float*)d_in[4];
  const float* bias     = (const float*)d_in[5];
  float* out = (float*)d_out;

  unsigned short* A2 = (unsigned short*)d_ws;                          // 67.1 MB
  unsigned short* W2 = (unsigned short*)((char*)d_ws + 67108864);      // 67.1 MB
  float*          Pp = (float*)((char*)d_ws + 134217728);              // 67.1 MB

  prep<<<dim3(4096), dim3(512), 0, stream>>>(x, rxd_perm, e_idx, signs, W, A2, W2);
  gemm_splitk<<<dim3(2 * Z_), dim3(512), 0, stream>>>(A2, W2, Pp);
  reduce_out<<<dim3(128), dim3(256), 0, stream>>>(Pp, bias, out);
}

// Round 4
// 333.245 us; speedup vs baseline: 1.0052x; 1.0052x over previous
//
#include <hip/hip_runtime.h>
#include <stdint.h>

#define B_ 64
#define C_ 4
#define R_ 64
#define E_ 512
#define P_ 4
#define OS_ 256
#define L_ 32768          // R_*E_
#define K_ 131072         // L_*P_
#define M_ 256            // B_*C_

#define BM 256
#define BN 128
#define BK 32
#define Z_ 256            // split-K slices; grid = 512 = 2 blocks/CU
#define KCH (K_/Z_)       // 512
#define ITERS (KCH/BK)    // 16

typedef float  floatx4 __attribute__((ext_vector_type(4)));
typedef short  shortx8 __attribute__((ext_vector_type(8)));

// async global->LDS, 16 B per lane; LDS dest is wave-uniform base + lane*16
#define GLDS16(g, l) __builtin_amdgcn_global_load_lds(                      \
    (const __attribute__((address_space(1))) void*)(g),                     \
    (__attribute__((address_space(3))) void*)(l), 16, 0, 0)

static __device__ __forceinline__ unsigned short f2bf(float f) {
  union { float f; unsigned int u; } v; v.f = f;
  unsigned int u = v.u;
  u += 0x7fffu + ((u >> 16) & 1u);   // RNE
  return (unsigned short)(u >> 16);
}

// ---------------------------------------------------------------------------
// prep: blocks 0..255 = convW (pure streaming, launched first for overlap),
//       blocks 256..767 = build_A (gather/VALU-bound).
// A2/W2 layout (k-slab granules): X2[k8][col][8] bf16; a gemm fragment for
// lane `col` is granule (k8, col) = 16 B contiguous; a BK=32 tile is fully
// contiguous in HBM.
// All wave-stores are >=512B-contiguous segments (R3's 16B@4KB-stride store
// pattern was channel-camped: 64 txns/instr on one 256B-interleaved channel).
// ---------------------------------------------------------------------------
__global__ __launch_bounds__(512) void prep(
    const float* __restrict__ x, const int* __restrict__ rxd_perm,
    const int* __restrict__ e_idx, const float* __restrict__ signs,
    const float* __restrict__ W,
    unsigned short* __restrict__ A2, unsigned short* __restrict__ W2) {
  __shared__ __align__(16) unsigned char smem[65536];   // 64 KB union
  const int t    = threadIdx.x;
  const int lane = t & 63;
  const int wv   = t >> 6;

  if (blockIdx.x < 256) {
    // ---- convW: W[n][k] f32 -> W2[k8][n][8] bf16, one 512-k chunk/block ----
    const int kb = blockIdx.x;            // 0..255
    unsigned short* T = (unsigned short*)smem;   // [64][64] granules, XOR swz

    #pragma unroll 1
    for (int nt = 0; nt < 4; ++nt) {
      const int n0 = nt * 64;
      // stage+convert: per instr a wave reads 2 KB contiguous of one n-row
      #pragma unroll
      for (int j = 0; j < 8; ++j) {
        const int n = j * 8 + wv;         // fixed per wave
        const float* wp = W + (size_t)(n0 + n) * K_ + (size_t)kb * 512 + lane * 8;
        const float4 a0 = *(const float4*)(wp);
        const float4 a1 = *(const float4*)(wp + 4);
        shortx8 g;
        g[0] = (short)f2bf(a0.x); g[1] = (short)f2bf(a0.y);
        g[2] = (short)f2bf(a0.z); g[3] = (short)f2bf(a0.w);
        g[4] = (short)f2bf(a1.x); g[5] = (short)f2bf(a1.y);
        g[6] = (short)f2bf(a1.z); g[7] = (short)f2bf(a1.w);
        *(shortx8*)(&T[((size_t)lane * 64 + (n ^ lane)) * 8]) = g;   // k8loc=lane
      }
      __syncthreads();
      // store: per instr a wave writes 1 KB contiguous (one k8 row-slice)
      #pragma unroll
      for (int i = 0; i < 8; ++i) {
        const int k8loc = wv * 8 + i;
        const shortx8 g = *(const shortx8*)(&T[((size_t)k8loc * 64 + (lane ^ k8loc)) * 8]);
        *(shortx8*)(W2 + ((size_t)(kb * 64 + k8loc) * 256 + n0 + lane) * 8) = g;
      }
      __syncthreads();
    }

  } else {
    // ---- build_A: block = (r, 32-bc chunk); xr = 32 rows x 2 KB ----
    const int blk = blockIdx.x - 256;     // 0..511
    const int r   = blk >> 3;
    const int bcg = blk & 7;
    float (*xr)[E_] = (float(*)[E_])smem; // [32][512] f32 = 64 KB
    const int pr = rxd_perm[r];

    #pragma unroll
    for (int i = 0; i < 8; ++i) {         // 1 KB contiguous per wave-instr
      const int q   = i * 512 + t;
      const int row = q >> 7;             // 0..31
      const int c4  = q & 127;
      *(float4*)(&xr[row][c4 * 4]) =
          *(const float4*)(x + ((size_t)(bcg * 32 + row) * R_ + pr) * E_ + c4 * 4);
    }
    __syncthreads();

    const int bcl = t & 31;
    const int bc  = bcg * 32 + bcl;
    const float* xp = xr[bcl];

    #pragma unroll 1
    for (int task = 0; task < 4; ++task) {
      const int l  = task * 16 + (t >> 5);   // e-granule 0..63
      const int e0 = l * 8;

      float v[4][8];
      #pragma unroll
      for (int i = 0; i < 8; ++i) {
        const uint4  ei = *(const uint4*)(e_idx + (size_t)(e0 + i) * 4);
        const float4 sg = *(const float4*)(signs + (size_t)(e0 + i) * 4);
        v[0][i] = xp[ei.x] * sg.x;
        v[1][i] = xp[ei.y] * sg.y;
        v[2][i] = xp[ei.z] * sg.z;
        v[3][i] = xp[ei.w] * sg.w;
      }

      // k8 = p*4096 + r*64 + l; store granule (k8, bc).
      // Per wave-instr: 2 segments of 32 lanes x 16 B = 512 B contiguous.
      unsigned short* dst = A2 + ((size_t)(r * 64 + l) * 256 + bc) * 8;
      shortx8 o;

      // p=0: passthrough
      #pragma unroll
      for (int i = 0; i < 8; ++i) o[i] = (short)f2bf(v[0][i]);
      *(shortx8*)(dst) = o;

      // p=1: k=2 windows, first-max wins
      #pragma unroll
      for (int j = 0; j < 4; ++j) {
        const float a = v[1][2 * j], b = v[1][2 * j + 1];
        const bool first = (a >= b);
        o[2 * j]     = (short)f2bf(first ? a : 0.0f);
        o[2 * j + 1] = (short)f2bf(first ? 0.0f : b);
      }
      *(shortx8*)(dst + (size_t)4096 * 256 * 8) = o;

      // p=2: k=4 windows
      #pragma unroll
      for (int j = 0; j < 2; ++j) {
        int am = 0; float m = v[2][4 * j];
        #pragma unroll
        for (int i = 1; i < 4; ++i)
          if (v[2][4 * j + i] > m) { m = v[2][4 * j + i]; am = i; }
        #pragma unroll
        for (int i = 0; i < 4; ++i) o[4 * j + i] = (short)f2bf(i == am ? m : 0.0f);
      }
      *(shortx8*)(dst + (size_t)2 * 4096 * 256 * 8) = o;

      // p=3: k=8 window
      {
        int am = 0; float m = v[3][0];
        #pragma unroll
        for (int i = 1; i < 8; ++i)
          if (v[3][i] > m) { m = v[3][i]; am = i; }
        #pragma unroll
        for (int i = 0; i < 8; ++i) o[i] = (short)f2bf(i == am ? m : 0.0f);
      }
      *(shortx8*)(dst + (size_t)3 * 4096 * 256 * 8) = o;
    }
  }
}

// ---------------------------------------------------------------------------
// Split-K GEMM on k-slab layout (UNCHANGED from R3 — measured ~39 µs):
// per iter GLDS 16 KB (A2) + 8 KB (W2), fully contiguous; fragments read
// directly as 16-B granules. Double-buffered, 48 KB LDS -> 2 blocks/CU.
// ---------------------------------------------------------------------------
__global__ __launch_bounds__(512, 4) void gemm_splitk(
    const unsigned short* __restrict__ A2, const unsigned short* __restrict__ W2,
    float* __restrict__ Pp) {
  __shared__ unsigned short As[2][4 * 256 * 8];   // 2 x 16 KB
  __shared__ unsigned short Ws[2][4 * 128 * 8];   // 2 x 8 KB
  const int t    = threadIdx.x;
  const int lane = t & 63;
  const int wv   = t >> 6;                  // 0..7

  const int id = blockIdx.x;                // 0..511
  const int ny = (id >> 3) & 1;
  const int z  = (id & 7) | ((id >> 4) << 3);
  const int nBase = ny * BN;

  const int wm   = (wv >> 1) * 64;
  const int wn   = (wv & 1) * 64;
  const int lrow = lane & 15;
  const int quad = lane >> 4;

  floatx4 acc[4][4];
  #pragma unroll
  for (int i = 0; i < 4; ++i)
    #pragma unroll
    for (int j = 0; j < 4; ++j) acc[i][j] = {0.f, 0.f, 0.f, 0.f};

  auto stage = [&](int buf, int it) {
    const size_t g0 = (size_t)(z * 64 + it * 4) * 256;   // 4 slabs x 256 granules
    #pragma unroll
    for (int c = 0; c < 2; ++c) {
      const int slot = (wv * 2 + c) * 64 + lane;         // 0..1023
      GLDS16(A2 + (g0 + slot) * 8, &As[buf][slot * 8]);
    }
    const int wslot = wv * 64 + lane;                    // 0..511
    const int slab  = wslot >> 7;                        // uniform per wave
    const int nloc  = wslot & 127;
    GLDS16(W2 + (g0 + (size_t)slab * 256 + nBase + nloc) * 8, &Ws[buf][wslot * 8]);
  };
  auto compute = [&](int buf) {
    shortx8 af[4], wf[4];
    #pragma unroll
    for (int ti = 0; ti < 4; ++ti)
      af[ti] = *(const shortx8*)(&As[buf][(quad * 256 + wm + ti * 16 + lrow) * 8]);
    #pragma unroll
    for (int tj = 0; tj < 4; ++tj)
      wf[tj] = *(const shortx8*)(&Ws[buf][(quad * 128 + wn + tj * 16 + lrow) * 8]);
    #pragma unroll
    for (int ti = 0; ti < 4; ++ti)
      #pragma unroll
      for (int tj = 0; tj < 4; ++tj)
        acc[ti][tj] = __builtin_amdgcn_mfma_f32_16x16x32_bf16(
            af[ti], wf[tj], acc[ti][tj], 0, 0, 0);
  };

  stage(0, 0);
  __syncthreads();

  for (int it = 0; it < ITERS; ++it) {
    const int b = it & 1;
    if (it + 1 < ITERS) stage(b ^ 1, it + 1);  // fire-and-forget prefetch
    compute(b);
    __syncthreads();                            // vmcnt(0): buffer b^1 ready
  }

  float* Pz = Pp + (size_t)z * (M_ * OS_);
  #pragma unroll
  for (int ti = 0; ti < 4; ++ti)
    #pragma unroll
    for (int tj = 0; tj < 4; ++tj)
      #pragma unroll
      for (int j = 0; j < 4; ++j) {
        const int m = wm + ti * 16 + quad * 4 + j;
        const int n = nBase + wn + tj * 16 + lrow;
        Pz[(size_t)m * OS_ + n] = acc[ti][tj][j];
      }
}

// out[m,n] = bias[n] + sum_z P[z,m,n]; 2-way z-split, halves combined via LDS
__global__ __launch_bounds__(256) void reduce_out(
    const float* __restrict__ Pp, const float* __restrict__ bias,
    float* __restrict__ out) {
  __shared__ float4 part[128];
  const int t    = threadIdx.x;                    // 0..255
  const int i4   = blockIdx.x * 128 + (t & 127);   // 0..16383
  const int half = t >> 7;
  const float* p = Pp + (size_t)i4 * 4 + (size_t)half * 128 * (M_ * OS_);
  float4 s = {0.f, 0.f, 0.f, 0.f};
  #pragma unroll 8
  for (int zz = 0; zz < 128; ++zz) {
    const float4 v = *(const float4*)(p + (size_t)zz * (M_ * OS_));
    s.x += v.x; s.y += v.y; s.z += v.z; s.w += v.w;
  }
  if (half) part[t & 127] = s;
  __syncthreads();
  if (!half) {
    const float4 q = part[t];
    const float4 bb = *(const float4*)(bias + ((i4 * 4) & (OS_ - 1)));
    float4 o = {s.x + q.x + bb.x, s.y + q.y + bb.y,
                s.z + q.z + bb.z, s.w + q.w + bb.w};
    *(float4*)(out + (size_t)i4 * 4) = o;
  }
}

extern "C" void kernel_launch(void* const* d_in, const int* in_sizes, int n_in,
                              void* d_out, int out_size, void* d_ws, size_t ws_size,
                              hipStream_t stream) {
  const float* x        = (const float*)d_in[0];
  const int*   rxd_perm = (const int*)d_in[1];
  const int*   e_idx    = (const int*)d_in[2];
  const float* signs    = (const float*)d_in[3];
  const float* W        = (const float*)d_in[4];
  const float* bias     = (const float*)d_in[5];
  float* out = (float*)d_out;

  unsigned short* A2 = (unsigned short*)d_ws;                          // 67.1 MB
  unsigned short* W2 = (unsigned short*)((char*)d_ws + 67108864);      // 67.1 MB
  float*          Pp = (float*)((char*)d_ws + 134217728);              // 67.1 MB

  prep<<<dim3(768), dim3(512), 0, stream>>>(x, rxd_perm, e_idx, signs, W, A2, W2);
  gemm_splitk<<<dim3(2 * Z_), dim3(512), 0, stream>>>(A2, W2, Pp);
  reduce_out<<<dim3(128), dim3(256), 0, stream>>>(Pp, bias, out);
}

// Round 5
// 304.027 us; speedup vs baseline: 1.1018x; 1.0961x over previous
//
#include <hip/hip_runtime.h>
#include <stdint.h>

#define B_ 64
#define C_ 4
#define R_ 64
#define E_ 512
#define P_ 4
#define OS_ 256
#define L_ 32768          // R_*E_
#define K_ 131072         // L_*P_
#define M_ 256            // B_*C_

#define BM 256
#define BN 128
#define BK 32
#define Z_ 256            // split-K slices; grid = 512 = 2 blocks/CU
#define KCH (K_/Z_)       // 512
#define ITERS (KCH/BK)    // 16

#define XSTR 513          // padded x-row stride (f32): bank=(bcl+e)%32

typedef float  floatx4 __attribute__((ext_vector_type(4)));
typedef short  shortx8 __attribute__((ext_vector_type(8)));

// async global->LDS, 16 B per lane; LDS dest is wave-uniform base + lane*16
#define GLDS16(g, l) __builtin_amdgcn_global_load_lds(                      \
    (const __attribute__((address_space(1))) void*)(g),                     \
    (__attribute__((address_space(3))) void*)(l), 16, 0, 0)

static __device__ __forceinline__ unsigned short f2bf(float f) {
  union { float f; unsigned int u; } v; v.f = f;
  unsigned int u = v.u;
  u += 0x7fffu + ((u >> 16) & 1u);   // RNE
  return (unsigned short)(u >> 16);
}

// ---------------------------------------------------------------------------
// prep: blocks 0..255 = convW (pure streaming), 256..767 = build_A.
// A2/W2 k-slab granule layout: X2[k8][col][8] bf16 (gemm reads it as-is).
// build_A: stores contiguous per half-wave (R4 fix, WRITE ideal) AND gather
// conflict-free via XSTR=513 row pad (R4's 32-way same-column conflict:
// 32.5M cycles -> ~0). Staging uses float2 + scalar ds_write (2/bank = free).
// ---------------------------------------------------------------------------
__global__ __launch_bounds__(512) void prep(
    const float* __restrict__ x, const int* __restrict__ rxd_perm,
    const int* __restrict__ e_idx, const float* __restrict__ signs,
    const float* __restrict__ W,
    unsigned short* __restrict__ A2, unsigned short* __restrict__ W2) {
  __shared__ __align__(16) unsigned char smem[32 * XSTR * 4];  // 65664 B
  const int t    = threadIdx.x;
  const int lane = t & 63;
  const int wv   = t >> 6;

  if (blockIdx.x < 256) {
    // ---- convW: W[n][k] f32 -> W2[k8][n][8] bf16, one 512-k chunk/block ----
    const int kb = blockIdx.x;            // 0..255
    unsigned short* T = (unsigned short*)smem;   // [64][64] granules, XOR swz

    #pragma unroll 1
    for (int nt = 0; nt < 4; ++nt) {
      const int n0 = nt * 64;
      // stage+convert: per instr a wave reads 2 KB contiguous of one n-row
      #pragma unroll
      for (int j = 0; j < 8; ++j) {
        const int n = j * 8 + wv;         // fixed per wave
        const float* wp = W + (size_t)(n0 + n) * K_ + (size_t)kb * 512 + lane * 8;
        const float4 a0 = *(const float4*)(wp);
        const float4 a1 = *(const float4*)(wp + 4);
        shortx8 g;
        g[0] = (short)f2bf(a0.x); g[1] = (short)f2bf(a0.y);
        g[2] = (short)f2bf(a0.z); g[3] = (short)f2bf(a0.w);
        g[4] = (short)f2bf(a1.x); g[5] = (short)f2bf(a1.y);
        g[6] = (short)f2bf(a1.z); g[7] = (short)f2bf(a1.w);
        *(shortx8*)(&T[((size_t)lane * 64 + (n ^ lane)) * 8]) = g;   // k8loc=lane
      }
      __syncthreads();
      // store: per instr a wave writes 1 KB contiguous (one k8 row-slice)
      #pragma unroll
      for (int i = 0; i < 8; ++i) {
        const int k8loc = wv * 8 + i;
        const shortx8 g = *(const shortx8*)(&T[((size_t)k8loc * 64 + (lane ^ k8loc)) * 8]);
        *(shortx8*)(W2 + ((size_t)(kb * 64 + k8loc) * 256 + n0 + lane) * 8) = g;
      }
      __syncthreads();
    }

  } else {
    // ---- build_A: block = (r, 32-bc chunk); xr[32][XSTR] padded ----
    const int blk = blockIdx.x - 256;     // 0..511
    const int r   = blk >> 3;
    const int bcg = blk & 7;
    float* xr = (float*)smem;
    const int pr = rxd_perm[r];

    // stage: wave wv owns rows wv*4..wv*4+3; per instr 2 rows x 256 B global,
    // scalar LDS writes at banks (row+e)%32: parities interleave -> 2/bank.
    #pragma unroll
    for (int i = 0; i < 2; ++i) {
      const int row = wv * 4 + i * 2 + (lane >> 5);
      const float* xsrc = x + ((size_t)(bcg * 32 + row) * R_ + pr) * E_;
      float* xd = xr + (size_t)row * XSTR;
      #pragma unroll
      for (int pass = 0; pass < 8; ++pass) {
        const int e = pass * 64 + (lane & 31) * 2;
        const float2 v = *(const float2*)(xsrc + e);
        xd[e]     = v.x;
        xd[e + 1] = v.y;
      }
    }
    __syncthreads();

    const int bcl = t & 31;
    const int bc  = bcg * 32 + bcl;
    const float* xp = xr + (size_t)bcl * XSTR;

    #pragma unroll 1
    for (int task = 0; task < 4; ++task) {
      const int l  = task * 16 + (t >> 5);   // e-granule 0..63 (same per half-wave)
      const int e0 = l * 8;

      float v[4][8];
      #pragma unroll
      for (int i = 0; i < 8; ++i) {
        const uint4  ei = *(const uint4*)(e_idx + (size_t)(e0 + i) * 4);
        const float4 sg = *(const float4*)(signs + (size_t)(e0 + i) * 4);
        v[0][i] = xp[ei.x] * sg.x;
        v[1][i] = xp[ei.y] * sg.y;
        v[2][i] = xp[ei.z] * sg.z;
        v[3][i] = xp[ei.w] * sg.w;
      }

      // k8 = p*4096 + r*64 + l; store granule (k8, bc).
      // Per half-wave: 32 lanes x 16 B = 512 B contiguous.
      unsigned short* dst = A2 + ((size_t)(r * 64 + l) * 256 + bc) * 8;
      shortx8 o;

      // p=0: passthrough
      #pragma unroll
      for (int i = 0; i < 8; ++i) o[i] = (short)f2bf(v[0][i]);
      *(shortx8*)(dst) = o;

      // p=1: k=2 windows, first-max wins
      #pragma unroll
      for (int j = 0; j < 4; ++j) {
        const float a = v[1][2 * j], b = v[1][2 * j + 1];
        const bool first = (a >= b);
        o[2 * j]     = (short)f2bf(first ? a : 0.0f);
        o[2 * j + 1] = (short)f2bf(first ? 0.0f : b);
      }
      *(shortx8*)(dst + (size_t)4096 * 256 * 8) = o;

      // p=2: k=4 windows
      #pragma unroll
      for (int j = 0; j < 2; ++j) {
        int am = 0; float m = v[2][4 * j];
        #pragma unroll
        for (int i = 1; i < 4; ++i)
          if (v[2][4 * j + i] > m) { m = v[2][4 * j + i]; am = i; }
        #pragma unroll
        for (int i = 0; i < 4; ++i) o[4 * j + i] = (short)f2bf(i == am ? m : 0.0f);
      }
      *(shortx8*)(dst + (size_t)2 * 4096 * 256 * 8) = o;

      // p=3: k=8 window
      {
        int am = 0; float m = v[3][0];
        #pragma unroll
        for (int i = 1; i < 8; ++i)
          if (v[3][i] > m) { m = v[3][i]; am = i; }
        #pragma unroll
        for (int i = 0; i < 8; ++i) o[i] = (short)f2bf(i == am ? m : 0.0f);
      }
      *(shortx8*)(dst + (size_t)3 * 4096 * 256 * 8) = o;
    }
  }
}

// ---------------------------------------------------------------------------
// Split-K GEMM on k-slab layout (UNCHANGED — measured ~39 µs): per iter GLDS
// 16 KB (A2) + 8 KB (W2), fully contiguous; fragments read directly as 16-B
// granules. Double-buffered, 48 KB LDS -> 2 blocks/CU.
// ---------------------------------------------------------------------------
__global__ __launch_bounds__(512, 4) void gemm_splitk(
    const unsigned short* __restrict__ A2, const unsigned short* __restrict__ W2,
    float* __restrict__ Pp) {
  __shared__ unsigned short As[2][4 * 256 * 8];   // 2 x 16 KB
  __shared__ unsigned short Ws[2][4 * 128 * 8];   // 2 x 8 KB
  const int t    = threadIdx.x;
  const int lane = t & 63;
  const int wv   = t >> 6;                  // 0..7

  const int id = blockIdx.x;                // 0..511
  const int ny = (id >> 3) & 1;
  const int z  = (id & 7) | ((id >> 4) << 3);
  const int nBase = ny * BN;

  const int wm   = (wv >> 1) * 64;
  const int wn   = (wv & 1) * 64;
  const int lrow = lane & 15;
  const int quad = lane >> 4;

  floatx4 acc[4][4];
  #pragma unroll
  for (int i = 0; i < 4; ++i)
    #pragma unroll
    for (int j = 0; j < 4; ++j) acc[i][j] = {0.f, 0.f, 0.f, 0.f};

  auto stage = [&](int buf, int it) {
    const size_t g0 = (size_t)(z * 64 + it * 4) * 256;   // 4 slabs x 256 granules
    #pragma unroll
    for (int c = 0; c < 2; ++c) {
      const int slot = (wv * 2 + c) * 64 + lane;         // 0..1023
      GLDS16(A2 + (g0 + slot) * 8, &As[buf][slot * 8]);
    }
    const int wslot = wv * 64 + lane;                    // 0..511
    const int slab  = wslot >> 7;                        // uniform per wave
    const int nloc  = wslot & 127;
    GLDS16(W2 + (g0 + (size_t)slab * 256 + nBase + nloc) * 8, &Ws[buf][wslot * 8]);
  };
  auto compute = [&](int buf) {
    shortx8 af[4], wf[4];
    #pragma unroll
    for (int ti = 0; ti < 4; ++ti)
      af[ti] = *(const shortx8*)(&As[buf][(quad * 256 + wm + ti * 16 + lrow) * 8]);
    #pragma unroll
    for (int tj = 0; tj < 4; ++tj)
      wf[tj] = *(const shortx8*)(&Ws[buf][(quad * 128 + wn + tj * 16 + lrow) * 8]);
    #pragma unroll
    for (int ti = 0; ti < 4; ++ti)
      #pragma unroll
      for (int tj = 0; tj < 4; ++tj)
        acc[ti][tj] = __builtin_amdgcn_mfma_f32_16x16x32_bf16(
            af[ti], wf[tj], acc[ti][tj], 0, 0, 0);
  };

  stage(0, 0);
  __syncthreads();

  for (int it = 0; it < ITERS; ++it) {
    const int b = it & 1;
    if (it + 1 < ITERS) stage(b ^ 1, it + 1);  // fire-and-forget prefetch
    compute(b);
    __syncthreads();                            // vmcnt(0): buffer b^1 ready
  }

  float* Pz = Pp + (size_t)z * (M_ * OS_);
  #pragma unroll
  for (int ti = 0; ti < 4; ++ti)
    #pragma unroll
    for (int tj = 0; tj < 4; ++tj)
      #pragma unroll
      for (int j = 0; j < 4; ++j) {
        const int m = wm + ti * 16 + quad * 4 + j;
        const int n = nBase + wn + tj * 16 + lrow;
        Pz[(size_t)m * OS_ + n] = acc[ti][tj][j];
      }
}

// out[m,n] = bias[n] + sum_z P[z,m,n]; 2-way z-split, halves combined via LDS
__global__ __launch_bounds__(256) void reduce_out(
    const float* __restrict__ Pp, const float* __restrict__ bias,
    float* __restrict__ out) {
  __shared__ float4 part[128];
  const int t    = threadIdx.x;                    // 0..255
  const int i4   = blockIdx.x * 128 + (t & 127);   // 0..16383
  const int half = t >> 7;
  const float* p = Pp + (size_t)i4 * 4 + (size_t)half * 128 * (M_ * OS_);
  float4 s = {0.f, 0.f, 0.f, 0.f};
  #pragma unroll 8
  for (int zz = 0; zz < 128; ++zz) {
    const float4 v = *(const float4*)(p + (size_t)zz * (M_ * OS_));
    s.x += v.x; s.y += v.y; s.z += v.z; s.w += v.w;
  }
  if (half) part[t & 127] = s;
  __syncthreads();
  if (!half) {
    const float4 q = part[t];
    const float4 bb = *(const float4*)(bias + ((i4 * 4) & (OS_ - 1)));
    float4 o = {s.x + q.x + bb.x, s.y + q.y + bb.y,
                s.z + q.z + bb.z, s.w + q.w + bb.w};
    *(float4*)(out + (size_t)i4 * 4) = o;
  }
}

extern "C" void kernel_launch(void* const* d_in, const int* in_sizes, int n_in,
                              void* d_out, int out_size, void* d_ws, size_t ws_size,
                              hipStream_t stream) {
  const float* x        = (const float*)d_in[0];
  const int*   rxd_perm = (const int*)d_in[1];
  const int*   e_idx    = (const int*)d_in[2];
  const float* signs    = (const float*)d_in[3];
  const float* W        = (const float*)d_in[4];
  const float* bias     = (const float*)d_in[5];
  float* out = (float*)d_out;

  unsigned short* A2 = (unsigned short*)d_ws;                          // 67.1 MB
  unsigned short* W2 = (unsigned short*)((char*)d_ws + 67108864);      // 67.1 MB
  float*          Pp = (float*)((char*)d_ws + 134217728);              // 67.1 MB

  prep<<<dim3(768), dim3(512), 0, stream>>>(x, rxd_perm, e_idx, signs, W, A2, W2);
  gemm_splitk<<<dim3(2 * Z_), dim3(512), 0, stream>>>(A2, W2, Pp);
  reduce_out<<<dim3(128), dim3(256), 0, stream>>>(Pp, bias, out);
}

// Round 6
// 302.706 us; speedup vs baseline: 1.1066x; 1.0044x over previous
//
#include <hip/hip_runtime.h>
#include <stdint.h>

#define B_ 64
#define C_ 4
#define R_ 64
#define E_ 512
#define P_ 4
#define OS_ 256
#define L_ 32768          // R_*E_
#define K_ 131072         // L_*P_
#define M_ 256            // B_*C_

#define BM 256
#define BN 128
#define BK 32
#define Z_ 256            // split-K slices; grid = 512 = 2 blocks/CU
#define KCH (K_/Z_)       // 512
#define ITERS (KCH/BK)    // 16

#define XSTR 513          // padded x-row stride (f32): bank=(bcl+e)%32

typedef float  floatx4 __attribute__((ext_vector_type(4)));
typedef short  shortx8 __attribute__((ext_vector_type(8)));

// async global->LDS, 16 B per lane; LDS dest is wave-uniform base + lane*16
#define GLDS16(g, l) __builtin_amdgcn_global_load_lds(                      \
    (const __attribute__((address_space(1))) void*)(g),                     \
    (__attribute__((address_space(3))) void*)(l), 16, 0, 0)

static __device__ __forceinline__ unsigned short f2bf(float f) {
  union { float f; unsigned int u; } v; v.f = f;
  unsigned int u = v.u;
  u += 0x7fffu + ((u >> 16) & 1u);   // RNE
  return (unsigned short)(u >> 16);
}

// ---------------------------------------------------------------------------
// convW_k: W[n][k] f32 -> W2[k8][n][8] bf16 (k-slab granules). Verified R5
// loop, re-gridded to 512 UNIFORM blocks (kb 0..255 x n-half 0..1, nt 4->2)
// so per-block work is homogeneous (R5's merged prep mixed 768KB convW blocks
// with 190KB build_A blocks -> straggler tail, occupancy 34%).
// ---------------------------------------------------------------------------
__global__ __launch_bounds__(512) void convW_k(
    const float* __restrict__ W, unsigned short* __restrict__ W2) {
  __shared__ __align__(16) unsigned short T[64 * 64 * 8];   // 64 KB
  const int t    = threadIdx.x;
  const int lane = t & 63;
  const int wv   = t >> 6;
  const int kb   = blockIdx.x >> 1;     // 0..255 (512-k chunk)
  const int nh   = blockIdx.x & 1;      // n-half

  #pragma unroll 1
  for (int nt = 0; nt < 2; ++nt) {
    const int n0 = nh * 128 + nt * 64;
    // stage+convert: per instr a wave reads 2 KB contiguous of one n-row
    #pragma unroll
    for (int j = 0; j < 8; ++j) {
      const int n = j * 8 + wv;         // 0..63 tile-local, fixed per wave
      const float* wp = W + (size_t)(n0 + n) * K_ + (size_t)kb * 512 + lane * 8;
      const float4 a0 = *(const float4*)(wp);
      const float4 a1 = *(const float4*)(wp + 4);
      shortx8 g;
      g[0] = (short)f2bf(a0.x); g[1] = (short)f2bf(a0.y);
      g[2] = (short)f2bf(a0.z); g[3] = (short)f2bf(a0.w);
      g[4] = (short)f2bf(a1.x); g[5] = (short)f2bf(a1.y);
      g[6] = (short)f2bf(a1.z); g[7] = (short)f2bf(a1.w);
      *(shortx8*)(&T[((size_t)lane * 64 + (n ^ lane)) * 8]) = g;   // k8loc=lane
    }
    __syncthreads();
    // store: per instr a wave writes 1 KB contiguous (one k8 row-slice)
    #pragma unroll
    for (int i = 0; i < 8; ++i) {
      const int k8loc = wv * 8 + i;
      const shortx8 g = *(const shortx8*)(&T[((size_t)k8loc * 64 + (lane ^ k8loc)) * 8]);
      *(shortx8*)(W2 + ((size_t)(kb * 64 + k8loc) * 256 + n0 + lane) * 8) = g;
    }
    __syncthreads();
  }
}

// ---------------------------------------------------------------------------
// build_A (verified R5 branch, now standalone): x -> A2[k8][bc][8] bf16.
// Contiguous half-wave stores + XSTR=513 conflict-free gather (262K conflict
// cycles measured).
// ---------------------------------------------------------------------------
__global__ __launch_bounds__(512) void build_A(
    const float* __restrict__ x, const int* __restrict__ rxd_perm,
    const int* __restrict__ e_idx, const float* __restrict__ signs,
    unsigned short* __restrict__ A2) {
  __shared__ __align__(16) float xr[32 * XSTR];   // 65664 B
  const int t    = threadIdx.x;
  const int lane = t & 63;
  const int wv   = t >> 6;

  const int blk = blockIdx.x;           // 0..511
  const int r   = blk >> 3;
  const int bcg = blk & 7;
  const int pr  = rxd_perm[r];

  // stage: wave wv owns rows wv*4..wv*4+3; per instr 2 rows x 256 B global,
  // scalar LDS writes at banks (row+e)%32: parities interleave -> 2/bank.
  #pragma unroll
  for (int i = 0; i < 2; ++i) {
    const int row = wv * 4 + i * 2 + (lane >> 5);
    const float* xsrc = x + ((size_t)(bcg * 32 + row) * R_ + pr) * E_;
    float* xd = xr + (size_t)row * XSTR;
    #pragma unroll
    for (int pass = 0; pass < 8; ++pass) {
      const int e = pass * 64 + (lane & 31) * 2;
      const float2 v = *(const float2*)(xsrc + e);
      xd[e]     = v.x;
      xd[e + 1] = v.y;
    }
  }
  __syncthreads();

  const int bcl = t & 31;
  const int bc  = bcg * 32 + bcl;
  const float* xp = xr + (size_t)bcl * XSTR;

  #pragma unroll 1
  for (int task = 0; task < 4; ++task) {
    const int l  = task * 16 + (t >> 5);   // e-granule 0..63 (same per half-wave)
    const int e0 = l * 8;

    float v[4][8];
    #pragma unroll
    for (int i = 0; i < 8; ++i) {
      const uint4  ei = *(const uint4*)(e_idx + (size_t)(e0 + i) * 4);
      const float4 sg = *(const float4*)(signs + (size_t)(e0 + i) * 4);
      v[0][i] = xp[ei.x] * sg.x;
      v[1][i] = xp[ei.y] * sg.y;
      v[2][i] = xp[ei.z] * sg.z;
      v[3][i] = xp[ei.w] * sg.w;
    }

    // k8 = p*4096 + r*64 + l; store granule (k8, bc).
    // Per half-wave: 32 lanes x 16 B = 512 B contiguous.
    unsigned short* dst = A2 + ((size_t)(r * 64 + l) * 256 + bc) * 8;
    shortx8 o;

    // p=0: passthrough
    #pragma unroll
    for (int i = 0; i < 8; ++i) o[i] = (short)f2bf(v[0][i]);
    *(shortx8*)(dst) = o;

    // p=1: k=2 windows, first-max wins
    #pragma unroll
    for (int j = 0; j < 4; ++j) {
      const float a = v[1][2 * j], b = v[1][2 * j + 1];
      const bool first = (a >= b);
      o[2 * j]     = (short)f2bf(first ? a : 0.0f);
      o[2 * j + 1] = (short)f2bf(first ? 0.0f : b);
    }
    *(shortx8*)(dst + (size_t)4096 * 256 * 8) = o;

    // p=2: k=4 windows
    #pragma unroll
    for (int j = 0; j < 2; ++j) {
      int am = 0; float m = v[2][4 * j];
      #pragma unroll
      for (int i = 1; i < 4; ++i)
        if (v[2][4 * j + i] > m) { m = v[2][4 * j + i]; am = i; }
      #pragma unroll
      for (int i = 0; i < 4; ++i) o[4 * j + i] = (short)f2bf(i == am ? m : 0.0f);
    }
    *(shortx8*)(dst + (size_t)2 * 4096 * 256 * 8) = o;

    // p=3: k=8 window
    {
      int am = 0; float m = v[3][0];
      #pragma unroll
      for (int i = 1; i < 8; ++i)
        if (v[3][i] > m) { m = v[3][i]; am = i; }
      #pragma unroll
      for (int i = 0; i < 8; ++i) o[i] = (short)f2bf(i == am ? m : 0.0f);
    }
    *(shortx8*)(dst + (size_t)3 * 4096 * 256 * 8) = o;
  }
}

// ---------------------------------------------------------------------------
// Split-K GEMM on k-slab layout (UNCHANGED — measured ~39 µs, at its traffic
// roofline ~43 µs): per iter GLDS 16 KB (A2) + 8 KB (W2), fully contiguous;
// fragments read directly as 16-B granules. Double-buffered, 48 KB LDS.
// ---------------------------------------------------------------------------
__global__ __launch_bounds__(512, 4) void gemm_splitk(
    const unsigned short* __restrict__ A2, const unsigned short* __restrict__ W2,
    float* __restrict__ Pp) {
  __shared__ unsigned short As[2][4 * 256 * 8];   // 2 x 16 KB
  __shared__ unsigned short Ws[2][4 * 128 * 8];   // 2 x 8 KB
  const int t    = threadIdx.x;
  const int lane = t & 63;
  const int wv   = t >> 6;                  // 0..7

  const int id = blockIdx.x;                // 0..511
  const int ny = (id >> 3) & 1;
  const int z  = (id & 7) | ((id >> 4) << 3);
  const int nBase = ny * BN;

  const int wm   = (wv >> 1) * 64;
  const int wn   = (wv & 1) * 64;
  const int lrow = lane & 15;
  const int quad = lane >> 4;

  floatx4 acc[4][4];
  #pragma unroll
  for (int i = 0; i < 4; ++i)
    #pragma unroll
    for (int j = 0; j < 4; ++j) acc[i][j] = {0.f, 0.f, 0.f, 0.f};

  auto stage = [&](int buf, int it) {
    const size_t g0 = (size_t)(z * 64 + it * 4) * 256;   // 4 slabs x 256 granules
    #pragma unroll
    for (int c = 0; c < 2; ++c) {
      const int slot = (wv * 2 + c) * 64 + lane;         // 0..1023
      GLDS16(A2 + (g0 + slot) * 8, &As[buf][slot * 8]);
    }
    const int wslot = wv * 64 + lane;                    // 0..511
    const int slab  = wslot >> 7;                        // uniform per wave
    const int nloc  = wslot & 127;
    GLDS16(W2 + (g0 + (size_t)slab * 256 + nBase + nloc) * 8, &Ws[buf][wslot * 8]);
  };
  auto compute = [&](int buf) {
    shortx8 af[4], wf[4];
    #pragma unroll
    for (int ti = 0; ti < 4; ++ti)
      af[ti] = *(const shortx8*)(&As[buf][(quad * 256 + wm + ti * 16 + lrow) * 8]);
    #pragma unroll
    for (int tj = 0; tj < 4; ++tj)
      wf[tj] = *(const shortx8*)(&Ws[buf][(quad * 128 + wn + tj * 16 + lrow) * 8]);
    #pragma unroll
    for (int ti = 0; ti < 4; ++ti)
      #pragma unroll
      for (int tj = 0; tj < 4; ++tj)
        acc[ti][tj] = __builtin_amdgcn_mfma_f32_16x16x32_bf16(
            af[ti], wf[tj], acc[ti][tj], 0, 0, 0);
  };

  stage(0, 0);
  __syncthreads();

  for (int it = 0; it < ITERS; ++it) {
    const int b = it & 1;
    if (it + 1 < ITERS) stage(b ^ 1, it + 1);  // fire-and-forget prefetch
    compute(b);
    __syncthreads();                            // vmcnt(0): buffer b^1 ready
  }

  float* Pz = Pp + (size_t)z * (M_ * OS_);
  #pragma unroll
  for (int ti = 0; ti < 4; ++ti)
    #pragma unroll
    for (int tj = 0; tj < 4; ++tj)
      #pragma unroll
      for (int j = 0; j < 4; ++j) {
        const int m = wm + ti * 16 + quad * 4 + j;
        const int n = nBase + wn + tj * 16 + lrow;
        Pz[(size_t)m * OS_ + n] = acc[ti][tj][j];
      }
}

// out[m,n] = bias[n] + sum_z P[z,m,n]; 2-way z-split, halves combined via LDS
__global__ __launch_bounds__(256) void reduce_out(
    const float* __restrict__ Pp, const float* __restrict__ bias,
    float* __restrict__ out) {
  __shared__ float4 part[128];
  const int t    = threadIdx.x;                    // 0..255
  const int i4   = blockIdx.x * 128 + (t & 127);   // 0..16383
  const int half = t >> 7;
  const float* p = Pp + (size_t)i4 * 4 + (size_t)half * 128 * (M_ * OS_);
  float4 s = {0.f, 0.f, 0.f, 0.f};
  #pragma unroll 8
  for (int zz = 0; zz < 128; ++zz) {
    const float4 v = *(const float4*)(p + (size_t)zz * (M_ * OS_));
    s.x += v.x; s.y += v.y; s.z += v.z; s.w += v.w;
  }
  if (half) part[t & 127] = s;
  __syncthreads();
  if (!half) {
    const float4 q = part[t];
    const float4 bb = *(const float4*)(bias + ((i4 * 4) & (OS_ - 1)));
    float4 o = {s.x + q.x + bb.x, s.y + q.y + bb.y,
                s.z + q.z + bb.z, s.w + q.w + bb.w};
    *(float4*)(out + (size_t)i4 * 4) = o;
  }
}

extern "C" void kernel_launch(void* const* d_in, const int* in_sizes, int n_in,
                              void* d_out, int out_size, void* d_ws, size_t ws_size,
                              hipStream_t stream) {
  const float* x        = (const float*)d_in[0];
  const int*   rxd_perm = (const int*)d_in[1];
  const int*   e_idx    = (const int*)d_in[2];
  const float* signs    = (const float*)d_in[3];
  const float* W        = (const float*)d_in[4];
  const float* bias     = (const float*)d_in[5];
  float* out = (float*)d_out;

  unsigned short* A2 = (unsigned short*)d_ws;                          // 67.1 MB
  unsigned short* W2 = (unsigned short*)((char*)d_ws + 67108864);      // 67.1 MB
  float*          Pp = (float*)((char*)d_ws + 134217728);              // 67.1 MB

  convW_k<<<dim3(512), dim3(512), 0, stream>>>(W, W2);
  build_A<<<dim3(512), dim3(512), 0, stream>>>(x, rxd_perm, e_idx, signs, A2);
  gemm_splitk<<<dim3(2 * Z_), dim3(512), 0, stream>>>(A2, W2, Pp);
  reduce_out<<<dim3(128), dim3(256), 0, stream>>>(Pp, bias, out);
}